// Round 6
// baseline (207.597 us; speedup 1.0000x reference)
//
#include <hip/hip_runtime.h>

// ---------------------------------------------------------------------------
// CrossSiloAggregator — fused single-pass, non-temporal, 8-row unroll.
//   out[r] = blend(local[r], foreign[map[r]])  if map[r] >= 0
//          = local[r]                          otherwise
//
// map init via hipMemsetAsync(0xFF) -> -1 (fast fill path).
// Traffic floor ~1.18 GB; measured fused BW ~6.05 TB/s (96% of the 6.29 TB/s
// float4-copy ceiling). This round: 8-row unroll + NT map read for the last
// few % of DRAM efficiency on the mixed R/W stream.
// ---------------------------------------------------------------------------

#define DIM 128

typedef float f4 __attribute__((ext_vector_type(4)));
typedef int   i4 __attribute__((ext_vector_type(4)));

__global__ void scatter_map_kernel(const int* __restrict__ idx,
                                   int* __restrict__ map, int M) {
    int m = blockIdx.x * blockDim.x + threadIdx.x;
    const int stride = gridDim.x * blockDim.x;
    for (; m < M; m += stride) map[idx[m]] = m;
}

__device__ __forceinline__ void do_row(const float* __restrict__ foreign_emb,
                                       float* __restrict__ out,
                                       long long row, int lane32, int fm,
                                       const f4& l, const f4& w0, const f4& w1,
                                       float bias) {
    if (fm < 0) {
        __builtin_nontemporal_store(l, (f4*)(out + row * DIM + lane32 * 4));
    } else {
        const f4 f = __builtin_nontemporal_load(
            (const f4*)(foreign_emb + (long long)fm * DIM + lane32 * 4));
        float p = l.x * w0.x + l.y * w0.y + l.z * w0.z + l.w * w0.w
                + f.x * w1.x + f.y * w1.y + f.z * w1.z + f.w * w1.w;
        #pragma unroll
        for (int off = 16; off > 0; off >>= 1) p += __shfl_xor(p, off);
        const float s = 1.0f / (1.0f + __expf(-(p + bias)));
        f4 o;
        o.x = s * l.x + (1.0f - s) * f.x;
        o.y = s * l.y + (1.0f - s) * f.y;
        o.z = s * l.z + (1.0f - s) * f.z;
        o.w = s * l.w + (1.0f - s) * f.w;
        __builtin_nontemporal_store(o, (f4*)(out + row * DIM + lane32 * 4));
    }
}

// One 32-lane half-wave per OCT (8 consecutive rows); lane owns a float4
// slice of each. A wave64 spans 16 adjacent rows = 8 KB contiguous per
// stream. All bulk streams non-temporal.
__global__ void __launch_bounds__(256)
fused_agg_kernel(const float* __restrict__ local_emb,
                 const float* __restrict__ foreign_emb,
                 const int* __restrict__ map,
                 const float* __restrict__ W_att,   // [256]
                 const float* __restrict__ b_att,   // [1]
                 float* __restrict__ out,
                 int n_rows) {
    const int lane32 = threadIdx.x & 31;

    const f4 w0 = *(const f4*)(W_att + lane32 * 4);
    const f4 w1 = *(const f4*)(W_att + DIM + lane32 * 4);
    const float bias = b_att[0];

    const long long hw = ((long long)blockIdx.x * blockDim.x + threadIdx.x) >> 5;
    const long long hw_stride = ((long long)gridDim.x * blockDim.x) >> 5;

    const long long n_octs = n_rows >> 3;

    for (long long q = hw; q < n_octs; q += hw_stride) {
        const long long r0 = q * 8;

        // Independent loads up front: 8 local f4 + 2 broadcast int4.
        const i4 fmA = __builtin_nontemporal_load((const i4*)(map + r0));
        const i4 fmB = __builtin_nontemporal_load((const i4*)(map + r0 + 4));
        f4 l[8];
        #pragma unroll
        for (int k = 0; k < 8; ++k) {
            l[k] = __builtin_nontemporal_load(
                (const f4*)(local_emb + (r0 + k) * DIM + lane32 * 4));
        }

        do_row(foreign_emb, out, r0 + 0, lane32, fmA.x, l[0], w0, w1, bias);
        do_row(foreign_emb, out, r0 + 1, lane32, fmA.y, l[1], w0, w1, bias);
        do_row(foreign_emb, out, r0 + 2, lane32, fmA.z, l[2], w0, w1, bias);
        do_row(foreign_emb, out, r0 + 3, lane32, fmA.w, l[3], w0, w1, bias);
        do_row(foreign_emb, out, r0 + 4, lane32, fmB.x, l[4], w0, w1, bias);
        do_row(foreign_emb, out, r0 + 5, lane32, fmB.y, l[5], w0, w1, bias);
        do_row(foreign_emb, out, r0 + 6, lane32, fmB.z, l[6], w0, w1, bias);
        do_row(foreign_emb, out, r0 + 7, lane32, fmB.w, l[7], w0, w1, bias);
    }

    // Tail rows (n_rows % 8).
    const long long tail_start = n_octs * 8;
    for (long long row = tail_start + hw; row < n_rows; row += hw_stride) {
        const int fm = map[row];
        const f4 l = __builtin_nontemporal_load(
            (const f4*)(local_emb + row * DIM + lane32 * 4));
        do_row(foreign_emb, out, row, lane32, fm, l, w0, w1, bias);
    }
}

extern "C" void kernel_launch(void* const* d_in, const int* in_sizes, int n_in,
                              void* d_out, int out_size, void* d_ws, size_t ws_size,
                              hipStream_t stream) {
    const float* local_emb   = (const float*)d_in[0];
    const float* foreign_emb = (const float*)d_in[1];
    const int*   indices     = (const int*)d_in[2];
    const float* W_att       = (const float*)d_in[3];
    const float* b_att       = (const float*)d_in[4];
    float* out = (float*)d_out;

    const int M = in_sizes[1] / DIM;          // 200,000 foreign rows
    const int n_rows = out_size / DIM;        // 1,000,000 local rows

    int* map = (int*)d_ws;                    // n_rows ints (4 MB)

    // map[r] = -1 via byte-fill 0xFF (fast fill path, graph-capture safe).
    hipMemsetAsync(map, 0xFF, (size_t)n_rows * sizeof(int), stream);
    scatter_map_kernel<<<(M + 255) / 256, 256, 0, stream>>>(indices, map, M);
    fused_agg_kernel<<<4096, 256, 0, stream>>>(
        local_emb, foreign_emb, map, W_att, b_att, out, n_rows);
}

// Round 7
// 201.799 us; speedup vs baseline: 1.0287x; 1.0287x over previous
//
#include <hip/hip_runtime.h>

// ---------------------------------------------------------------------------
// CrossSiloAggregator — fused single-pass, non-temporal, 4-row unroll.
//   out[r] = blend(local[r], foreign[map[r]])  if map[r] >= 0
//          = local[r]                          otherwise
//
// FINAL (reverted from 8-row unroll, which regressed 201.9 -> 207.6 us due
// to VGPR/vmcnt-chain pressure). Measured 201.9 us; structural floor ~195 us
// (1.181 GB min traffic @ 6.29 TB/s copy ceiling + map-prep overhead).
// ---------------------------------------------------------------------------

#define DIM 128

typedef float f4 __attribute__((ext_vector_type(4)));
typedef int   i4 __attribute__((ext_vector_type(4)));

__global__ void scatter_map_kernel(const int* __restrict__ idx,
                                   int* __restrict__ map, int M) {
    int m = blockIdx.x * blockDim.x + threadIdx.x;
    const int stride = gridDim.x * blockDim.x;
    for (; m < M; m += stride) map[idx[m]] = m;
}

__device__ __forceinline__ void do_row(const float* __restrict__ foreign_emb,
                                       float* __restrict__ out,
                                       long long row, int lane32, int fm,
                                       const f4& l, const f4& w0, const f4& w1,
                                       float bias) {
    if (fm < 0) {
        __builtin_nontemporal_store(l, (f4*)(out + row * DIM + lane32 * 4));
    } else {
        const f4 f = __builtin_nontemporal_load(
            (const f4*)(foreign_emb + (long long)fm * DIM + lane32 * 4));
        float p = l.x * w0.x + l.y * w0.y + l.z * w0.z + l.w * w0.w
                + f.x * w1.x + f.y * w1.y + f.z * w1.z + f.w * w1.w;
        #pragma unroll
        for (int off = 16; off > 0; off >>= 1) p += __shfl_xor(p, off);
        const float s = 1.0f / (1.0f + __expf(-(p + bias)));
        f4 o;
        o.x = s * l.x + (1.0f - s) * f.x;
        o.y = s * l.y + (1.0f - s) * f.y;
        o.z = s * l.z + (1.0f - s) * f.z;
        o.w = s * l.w + (1.0f - s) * f.w;
        __builtin_nontemporal_store(o, (f4*)(out + row * DIM + lane32 * 4));
    }
}

// One 32-lane half-wave per QUAD of consecutive rows; lane owns a float4
// slice of each. A wave64 touches 8 adjacent rows = 4 KB contiguous per
// stream. All bulk streams non-temporal. Map entries for the quad load as
// one broadcast int4.
__global__ void fused_agg_kernel(const float* __restrict__ local_emb,
                                 const float* __restrict__ foreign_emb,
                                 const int* __restrict__ map,
                                 const float* __restrict__ W_att,   // [256]
                                 const float* __restrict__ b_att,   // [1]
                                 float* __restrict__ out,
                                 int n_rows) {
    const int lane32 = threadIdx.x & 31;

    const f4 w0 = *(const f4*)(W_att + lane32 * 4);
    const f4 w1 = *(const f4*)(W_att + DIM + lane32 * 4);
    const float bias = b_att[0];

    const long long hw = ((long long)blockIdx.x * blockDim.x + threadIdx.x) >> 5;
    const long long hw_stride = ((long long)gridDim.x * blockDim.x) >> 5;

    const long long n_quads = n_rows >> 2;

    for (long long q = hw; q < n_quads; q += hw_stride) {
        const long long r0 = q * 4;

        // All independent loads up front: 4 local f4 + 1 broadcast int4.
        const i4 fm = *(const i4*)(map + r0);
        const f4 l0 = __builtin_nontemporal_load(
            (const f4*)(local_emb + (r0 + 0) * DIM + lane32 * 4));
        const f4 l1 = __builtin_nontemporal_load(
            (const f4*)(local_emb + (r0 + 1) * DIM + lane32 * 4));
        const f4 l2 = __builtin_nontemporal_load(
            (const f4*)(local_emb + (r0 + 2) * DIM + lane32 * 4));
        const f4 l3 = __builtin_nontemporal_load(
            (const f4*)(local_emb + (r0 + 3) * DIM + lane32 * 4));

        do_row(foreign_emb, out, r0 + 0, lane32, fm.x, l0, w0, w1, bias);
        do_row(foreign_emb, out, r0 + 1, lane32, fm.y, l1, w0, w1, bias);
        do_row(foreign_emb, out, r0 + 2, lane32, fm.z, l2, w0, w1, bias);
        do_row(foreign_emb, out, r0 + 3, lane32, fm.w, l3, w0, w1, bias);
    }

    // Tail rows (n_rows % 4).
    const long long tail_start = n_quads * 4;
    for (long long row = tail_start + hw; row < n_rows; row += hw_stride) {
        const int fm = map[row];
        const f4 l = __builtin_nontemporal_load(
            (const f4*)(local_emb + row * DIM + lane32 * 4));
        do_row(foreign_emb, out, row, lane32, fm, l, w0, w1, bias);
    }
}

extern "C" void kernel_launch(void* const* d_in, const int* in_sizes, int n_in,
                              void* d_out, int out_size, void* d_ws, size_t ws_size,
                              hipStream_t stream) {
    const float* local_emb   = (const float*)d_in[0];
    const float* foreign_emb = (const float*)d_in[1];
    const int*   indices     = (const int*)d_in[2];
    const float* W_att       = (const float*)d_in[3];
    const float* b_att       = (const float*)d_in[4];
    float* out = (float*)d_out;

    const int M = in_sizes[1] / DIM;          // 200,000 foreign rows
    const int n_rows = out_size / DIM;        // 1,000,000 local rows

    int* map = (int*)d_ws;                    // n_rows ints (4 MB)

    // map[r] = -1 via byte-fill 0xFF (fast fill path, graph-capture safe).
    hipMemsetAsync(map, 0xFF, (size_t)n_rows * sizeof(int), stream);
    scatter_map_kernel<<<(M + 255) / 256, 256, 0, stream>>>(indices, map, M);
    fused_agg_kernel<<<4096, 256, 0, stream>>>(
        local_emb, foreign_emb, map, W_att, b_att, out, n_rows);
}